// Round 6
// baseline (715.814 us; speedup 1.0000x reference)
//
#include <hip/hip_runtime.h>
#include <math.h>

// ---------------------------------------------------------------------------
// GraphSAGE 3-layer + classifier + log_softmax.
// Round 6: transform/gather split.
//   P = x@Wl, Q = x@Wr + bl  (dense transform, weights in LDS, shfl row bcast)
//   h = relu(mean P[src] + Q[v])  (pure-memory gather, max occupancy)
// Gather writes h into the Q half of PQ in place; transform runs in place on
// the Q half (each wave reads its row fully before writing).  CSR build with
// one-edge-per-thread kernels for full memory-level parallelism.
// ---------------------------------------------------------------------------

__global__ __launch_bounds__(256) void deg_kernel(const int* __restrict__ dst,
                                                  int* __restrict__ deg, int E) {
    int i = blockIdx.x * 256 + threadIdx.x;
    if (i < E) atomicAdd(&deg[dst[i]], 1);
}

__global__ __launch_bounds__(256) void blocksum_kernel(const int* __restrict__ deg,
                                                       int* __restrict__ bsum, int n) {
    int i = blockIdx.x * 256 + threadIdx.x;
    int v = (i < n) ? deg[i] : 0;
    #pragma unroll
    for (int off = 32; off > 0; off >>= 1) v += __shfl_down(v, off);
    __shared__ int ws_[4];
    if ((threadIdx.x & 63) == 0) ws_[threadIdx.x >> 6] = v;
    __syncthreads();
    if (threadIdx.x == 0) bsum[blockIdx.x] = ws_[0] + ws_[1] + ws_[2] + ws_[3];
}

__global__ __launch_bounds__(1024) void scan_bsum_kernel(int* __restrict__ bsum, int nb,
                                                         int* __restrict__ rowptr, int n) {
    __shared__ int s[1024];
    int t = threadIdx.x;
    int v = (t < nb) ? bsum[t] : 0;
    s[t] = v;
    __syncthreads();
    for (int off = 1; off < 1024; off <<= 1) {
        int u = (t >= off) ? s[t - off] : 0;
        __syncthreads();
        s[t] += u;
        __syncthreads();
    }
    if (t < nb) bsum[t] = s[t] - v;
    if (t == 0) rowptr[n] = s[1023];
}

__global__ __launch_bounds__(256) void rowptr_kernel(const int* __restrict__ deg,
                                                     const int* __restrict__ bsum,
                                                     int* __restrict__ rowptr, int n) {
    __shared__ int s[256];
    int t = threadIdx.x;
    int i = blockIdx.x * 256 + t;
    int v = (i < n) ? deg[i] : 0;
    s[t] = v;
    __syncthreads();
    for (int off = 1; off < 256; off <<= 1) {
        int u = (t >= off) ? s[t - off] : 0;
        __syncthreads();
        s[t] += u;
        __syncthreads();
    }
    if (i < n) rowptr[i] = bsum[blockIdx.x] + s[t] - v;
}

__global__ __launch_bounds__(256) void fill_kernel(const int* __restrict__ src,
                                                   const int* __restrict__ dst,
                                                   const int* __restrict__ rowptr,
                                                   int* __restrict__ cursor,
                                                   int* __restrict__ col, int E) {
    int i = blockIdx.x * 256 + threadIdx.x;
    if (i < E) {
        int d = dst[i];
        int p = atomicAdd(&cursor[d], 1);
        col[rowptr[d] + p] = src[i];
    }
}

// Dense transform: P[v] = in[v]@Wl ; Q[v] = in[v]@Wr + bl.
// Wave per node; lane = output feature; weights interleaved float2 in LDS
// (contiguous across lanes -> conflict-free ds_read_b64); input row broadcast
// via __shfl (readlane).  NOTE: no __restrict__ on in/PQ — they alias when
// running in place on the Q half.
__global__ __launch_bounds__(256) void transform_kernel(
    const float* in, int instride, float* PQ,
    const float* __restrict__ Wl, const float* __restrict__ bl,
    const float* __restrict__ Wr, int n)
{
    __shared__ float2 w2[64 * 64];
    __shared__ float sbl[64];
    int tid = threadIdx.x;
    for (int i = tid; i < 64 * 64; i += 256) w2[i] = make_float2(Wl[i], Wr[i]);
    if (tid < 64) sbl[tid] = bl[tid];
    __syncthreads();

    int wid = tid >> 6, lane = tid & 63;
    int w = blockIdx.x * 4 + wid;
    int nw = gridDim.x * 4;
    for (int v = w; v < n; v += nw) {
        float rowv = in[(size_t)v * instride + lane];  // read full row before write
        float p = 0.f, q = sbl[lane];
        #pragma unroll
        for (int k = 0; k < 64; ++k) {
            float m = __shfl(rowv, k);
            float2 ww = w2[k * 64 + lane];
            p = fmaf(m, ww.x, p);
            q = fmaf(m, ww.y, q);
        }
        PQ[(size_t)v * 128 + lane] = p;
        PQ[(size_t)v * 128 + 64 + lane] = q;
    }
}

// Pure-memory gather: h[v] = relu( mean_{s in N(v)} P[s] + Q[v] ), written
// into the Q slot of PQ (only node v's own wave ever touches Q[v]).
__global__ __launch_bounds__(256) void gather_kernel(
    float* __restrict__ PQ, const int* __restrict__ rowptr,
    const int* __restrict__ col, int n)
{
    int tid = threadIdx.x;
    int wid = tid >> 6, lane = tid & 63;
    int w = blockIdx.x * 4 + wid;
    int nw = gridDim.x * 4;
    for (int v = w; v < n; v += nw) {
        int s0 = rowptr[v], s1 = rowptr[v + 1];
        int deg = s1 - s0;
        float q = PQ[(size_t)v * 128 + 64 + lane];   // issued early, overlaps
        float acc = 0.f;
        for (int base = 0; base < deg; base += 64) {
            int rem = deg - base;
            int cnt = rem < 64 ? rem : 64;
            int ci = (lane < cnt) ? col[s0 + base + lane] : 0;
            int j = 0;
            for (; j + 8 <= cnt; j += 8) {
                int i0 = __shfl(ci, j + 0), i1 = __shfl(ci, j + 1);
                int i2 = __shfl(ci, j + 2), i3 = __shfl(ci, j + 3);
                int i4 = __shfl(ci, j + 4), i5 = __shfl(ci, j + 5);
                int i6 = __shfl(ci, j + 6), i7 = __shfl(ci, j + 7);
                float t0 = PQ[(size_t)i0 * 128 + lane];
                float t1 = PQ[(size_t)i1 * 128 + lane];
                float t2 = PQ[(size_t)i2 * 128 + lane];
                float t3 = PQ[(size_t)i3 * 128 + lane];
                float t4 = PQ[(size_t)i4 * 128 + lane];
                float t5 = PQ[(size_t)i5 * 128 + lane];
                float t6 = PQ[(size_t)i6 * 128 + lane];
                float t7 = PQ[(size_t)i7 * 128 + lane];
                acc += ((t0 + t1) + (t2 + t3)) + ((t4 + t5) + (t6 + t7));
            }
            for (; j + 4 <= cnt; j += 4) {
                int i0 = __shfl(ci, j + 0), i1 = __shfl(ci, j + 1);
                int i2 = __shfl(ci, j + 2), i3 = __shfl(ci, j + 3);
                float t0 = PQ[(size_t)i0 * 128 + lane];
                float t1 = PQ[(size_t)i1 * 128 + lane];
                float t2 = PQ[(size_t)i2 * 128 + lane];
                float t3 = PQ[(size_t)i3 * 128 + lane];
                acc += (t0 + t1) + (t2 + t3);
            }
            for (; j < cnt; ++j)
                acc += PQ[(size_t)__shfl(ci, j) * 128 + lane];
        }
        float res = acc / fmaxf((float)deg, 1.0f) + q;
        PQ[(size_t)v * 128 + 64 + lane] = fmaxf(res, 0.f);
    }
}

// Classifier + log_softmax on h rows living at PQ[v*128+64 .. +127].
__global__ __launch_bounds__(256) void cls_kernel(
    const float* __restrict__ h /* = PQ+64, stride 128 */,
    const float* __restrict__ Wc, const float* __restrict__ bc,
    float* __restrict__ out, int n)
{
    __shared__ float sW[64 * 10];
    __shared__ float sb[16];
    __shared__ float srow[4][4][64];
    int tid = threadIdx.x;
    for (int i = tid; i < 640; i += 256) sW[i] = Wc[i];
    if (tid < 10) sb[tid] = bc[tid];
    __syncthreads();

    int wid = tid >> 6, lane = tid & 63;
    int grp = lane >> 4, l16 = lane & 15;
    int w = blockIdx.x * 4 + wid;
    int nw = gridDim.x * 4;
    int ngroups = (n + 3) >> 2;
    for (int g = w; g < ngroups; g += nw) {
        int v0 = g * 4;
        #pragma unroll
        for (int r = 0; r < 4; ++r) {
            int vv = v0 + r;
            if (vv < n) srow[wid][r][lane] = h[(size_t)vv * 128 + lane];
        }
        int v = v0 + grp;
        float z = -INFINITY;
        if (v < n && l16 < 10) {
            z = sb[l16];
            #pragma unroll
            for (int k = 0; k < 64; ++k)
                z += srow[wid][grp][k] * sW[k * 10 + l16];
        }
        float m = z;
        for (int off = 8; off > 0; off >>= 1)
            m = fmaxf(m, __shfl_xor(m, off, 16));
        float e = (l16 < 10 && v < n) ? expf(z - m) : 0.f;
        float ssum = e;
        for (int off = 8; off > 0; off >>= 1)
            ssum += __shfl_xor(ssum, off, 16);
        if (v < n && l16 < 10)
            out[(size_t)v * 10 + l16] = z - m - logf(ssum);
    }
}

extern "C" void kernel_launch(void* const* d_in, const int* in_sizes, int n_in,
                              void* d_out, int out_size, void* d_ws, size_t ws_size,
                              hipStream_t stream) {
    const float* x   = (const float*)d_in[0];
    const int*   ei  = (const int*)d_in[1];
    const float* Wl1 = (const float*)d_in[2];
    const float* bl1 = (const float*)d_in[3];
    const float* Wr1 = (const float*)d_in[4];
    const float* Wl2 = (const float*)d_in[5];
    const float* bl2 = (const float*)d_in[6];
    const float* Wr2 = (const float*)d_in[7];
    const float* Wl3 = (const float*)d_in[8];
    const float* bl3 = (const float*)d_in[9];
    const float* Wr3 = (const float*)d_in[10];
    const float* Wc  = (const float*)d_in[11];
    const float* bc  = (const float*)d_in[12];
    float* outp = (float*)d_out;

    int n = in_sizes[0] / 64;
    int E = in_sizes[1] / 2;
    const int* srcp = ei;
    const int* dstp = ei + E;

    char* ws = (char*)d_ws;
    size_t off = 0;
    auto alloc = [&](size_t bytes) -> void* {
        void* p = ws + off;
        off += bytes;
        off = (off + 255) & ~(size_t)255;
        return p;
    };
    int nb = (n + 255) / 256;
    int nbE = (E + 255) / 256;
    int*   deg    = (int*)alloc((size_t)n * 4);
    int*   rowptr = (int*)alloc((size_t)(n + 1) * 4);
    int*   cursor = (int*)alloc((size_t)n * 4);
    int*   bsum   = (int*)alloc((size_t)nb * 4);
    int*   colv   = (int*)alloc((size_t)E * 4);
    float* PQ     = (float*)alloc((size_t)n * 128 * 4);
    (void)ws_size; (void)n_in; (void)out_size;

    hipMemsetAsync(deg, 0, (size_t)n * 4, stream);
    hipMemsetAsync(cursor, 0, (size_t)n * 4, stream);

    deg_kernel<<<nbE, 256, 0, stream>>>(dstp, deg, E);
    blocksum_kernel<<<nb, 256, 0, stream>>>(deg, bsum, n);
    scan_bsum_kernel<<<1, 1024, 0, stream>>>(bsum, nb, rowptr, n);
    rowptr_kernel<<<nb, 256, 0, stream>>>(deg, bsum, rowptr, n);
    fill_kernel<<<nbE, 256, 0, stream>>>(srcp, dstp, rowptr, cursor, colv, E);

    // layer 1
    transform_kernel<<<1024, 256, 0, stream>>>(x, 64, PQ, Wl1, bl1, Wr1, n);
    gather_kernel<<<2048, 256, 0, stream>>>(PQ, rowptr, colv, n);
    // layer 2 (in place: reads h from Q half, rewrites P/Q)
    transform_kernel<<<1024, 256, 0, stream>>>(PQ + 64, 128, PQ, Wl2, bl2, Wr2, n);
    gather_kernel<<<2048, 256, 0, stream>>>(PQ, rowptr, colv, n);
    // layer 3
    transform_kernel<<<1024, 256, 0, stream>>>(PQ + 64, 128, PQ, Wl3, bl3, Wr3, n);
    gather_kernel<<<2048, 256, 0, stream>>>(PQ, rowptr, colv, n);

    cls_kernel<<<1024, 256, 0, stream>>>(PQ + 64, Wc, bc, outp, n);
}

// Round 7
// 520.774 us; speedup vs baseline: 1.3745x; 1.3745x over previous
//
#include <hip/hip_runtime.h>
#include <hip/hip_bf16.h>
#include <math.h>

// ---------------------------------------------------------------------------
// GraphSAGE 3-layer + classifier + log_softmax.  Round 7.
//  - CSR via bucket counting sort (256-node buckets): LDS-aggregated histogram,
//    tiny scan, block-aggregated pair scatter (sequential runs per bucket),
//    per-bucket LDS CSR build with coalesced col writes.  No global scatter
//    atomics on hot lines -> kills the 107MB write amplification.
//  - P = h@Wl stored bf16 (rows 128B): halves gather traffic.  Q/h stay f32.
// ---------------------------------------------------------------------------

#define BSHIFT 8
#define BUCKET 256
#define MAXB 512            // max bucket count (n<=131072)
#define SCAT_EDGES 8192

// --- CSR pass 1: bucket histogram (LDS-aggregated) ---
__global__ __launch_bounds__(256) void hist_kernel(const int* __restrict__ dst,
                                                   int* __restrict__ ghist,
                                                   int E, int nbuck) {
    __shared__ int lh[MAXB];
    int t = threadIdx.x;
    lh[t] = 0; lh[t + 256] = 0;
    __syncthreads();
    int start = blockIdx.x * SCAT_EDGES;
    int end = min(E, start + SCAT_EDGES);
    for (int e = start + t; e < end; e += 256)
        atomicAdd(&lh[dst[e] >> BSHIFT], 1);
    __syncthreads();
    for (int b = t; b < nbuck; b += 256)
        if (lh[b]) atomicAdd(&ghist[b], lh[b]);
}

// --- CSR pass 2: scan bucket counts -> bbase (and init gcur) ---
__global__ __launch_bounds__(512) void scanb_kernel(const int* __restrict__ ghist,
                                                    int* __restrict__ bbase,
                                                    int* __restrict__ gcur,
                                                    int nbuck, int E) {
    __shared__ int s[MAXB];
    int t = threadIdx.x;
    int v = (t < nbuck) ? ghist[t] : 0;
    s[t] = v;
    __syncthreads();
    for (int off = 1; off < MAXB; off <<= 1) {
        int u = (t >= off) ? s[t - off] : 0;
        __syncthreads();
        s[t] += u;
        __syncthreads();
    }
    int excl = s[t] - v;
    if (t < nbuck) { bbase[t] = excl; gcur[t] = excl; }
    if (t == 0) bbase[nbuck] = E;
}

// --- CSR pass 3: scatter (src,dst) pairs into bucket segments, block-aggregated
// so each block writes ~contiguous runs per bucket. ---
__global__ __launch_bounds__(256) void scatter_kernel(const int* __restrict__ src,
                                                      const int* __restrict__ dst,
                                                      int* __restrict__ gcur,
                                                      int2* __restrict__ pairs,
                                                      int E, int nbuck) {
    __shared__ int lh[MAXB];
    __shared__ int lbase[MAXB];
    __shared__ int lcur[MAXB];
    int t = threadIdx.x;
    lh[t] = 0; lh[t + 256] = 0;
    lcur[t] = 0; lcur[t + 256] = 0;
    __syncthreads();
    int start = blockIdx.x * SCAT_EDGES;
    int end = min(E, start + SCAT_EDGES);
    for (int e = start + t; e < end; e += 256)
        atomicAdd(&lh[dst[e] >> BSHIFT], 1);
    __syncthreads();
    for (int b = t; b < nbuck; b += 256)
        if (lh[b]) lbase[b] = atomicAdd(&gcur[b], lh[b]);
    __syncthreads();
    for (int e = start + t; e < end; e += 256) {
        int d = dst[e];
        int b = d >> BSHIFT;
        int slot = atomicAdd(&lcur[b], 1);
        pairs[lbase[b] + slot] = make_int2(src[e], d);
    }
}

// --- CSR pass 4: per-bucket local CSR in LDS; coalesced col writes into the
// bucket's own contiguous segment. ---
__global__ __launch_bounds__(256) void build_kernel(const int2* __restrict__ pairs,
                                                    const int* __restrict__ bbase,
                                                    int* __restrict__ rowptr,
                                                    int* __restrict__ col,
                                                    int n, int E) {
    __shared__ int ldeg[BUCKET];
    __shared__ int pre[BUCKET];
    __shared__ int cur[BUCKET];
    int t = threadIdx.x;
    int nbase = blockIdx.x << BSHIFT;
    int e0 = bbase[blockIdx.x], e1 = bbase[blockIdx.x + 1];
    ldeg[t] = 0; cur[t] = 0;
    __syncthreads();
    for (int e = e0 + t; e < e1; e += 256)
        atomicAdd(&ldeg[pairs[e].y - nbase], 1);
    __syncthreads();
    int v = ldeg[t];
    pre[t] = v;
    __syncthreads();
    for (int off = 1; off < 256; off <<= 1) {
        int u = (t >= off) ? pre[t - off] : 0;
        __syncthreads();
        pre[t] += u;
        __syncthreads();
    }
    int excl = pre[t] - v;
    __syncthreads();
    pre[t] = excl;
    __syncthreads();
    int node = nbase + t;
    if (node < n) rowptr[node] = e0 + excl;
    if (blockIdx.x == 0 && t == 0) rowptr[n] = E;
    for (int e = e0 + t; e < e1; e += 256) {
        int2 p = pairs[e];
        int l = p.y - nbase;
        int pos = atomicAdd(&cur[l], 1);
        col[e0 + pre[l] + pos] = p.x;
    }
}

// --- Dense transform: P[v] = in[v]@Wl (bf16) ; Q[v] = in[v]@Wr + bl (f32).
// In-place on Qh for layers 2/3 (wave owns its row). ---
__global__ __launch_bounds__(256) void transform_kernel(
    const float* in, float* Qh, __hip_bfloat16* __restrict__ Pb,
    const float* __restrict__ Wl, const float* __restrict__ bl,
    const float* __restrict__ Wr, int n)
{
    __shared__ float2 w2[64 * 64];
    __shared__ float sbl[64];
    int tid = threadIdx.x;
    for (int i = tid; i < 64 * 64; i += 256) w2[i] = make_float2(Wl[i], Wr[i]);
    if (tid < 64) sbl[tid] = bl[tid];
    __syncthreads();

    int wid = tid >> 6, lane = tid & 63;
    int w = blockIdx.x * 4 + wid;
    int nw = gridDim.x * 4;
    for (int v = w; v < n; v += nw) {
        float rowv = in[(size_t)v * 64 + lane];
        float p = 0.f, q = sbl[lane];
        #pragma unroll
        for (int k = 0; k < 64; ++k) {
            float m = __shfl(rowv, k);
            float2 ww = w2[k * 64 + lane];
            p = fmaf(m, ww.x, p);
            q = fmaf(m, ww.y, q);
        }
        Pb[(size_t)v * 64 + lane] = __float2bfloat16(p);
        Qh[(size_t)v * 64 + lane] = q;
    }
}

// --- Pure-memory gather: h[v] = relu( mean_{s in N(v)} P[s] + Q[v] ),
// written back into Qh[v]. ---
__global__ __launch_bounds__(256) void gather_kernel(
    const __hip_bfloat16* __restrict__ Pb, float* __restrict__ Qh,
    const int* __restrict__ rowptr, const int* __restrict__ col, int n)
{
    int tid = threadIdx.x;
    int wid = tid >> 6, lane = tid & 63;
    int w = blockIdx.x * 4 + wid;
    int nw = gridDim.x * 4;
    for (int v = w; v < n; v += nw) {
        int s0 = rowptr[v], s1 = rowptr[v + 1];
        int deg = s1 - s0;
        float q = Qh[(size_t)v * 64 + lane];
        float acc = 0.f;
        for (int base = 0; base < deg; base += 64) {
            int rem = deg - base;
            int cnt = rem < 64 ? rem : 64;
            int ci = (lane < cnt) ? col[s0 + base + lane] : 0;
            int j = 0;
            for (; j + 8 <= cnt; j += 8) {
                int i0 = __shfl(ci, j + 0), i1 = __shfl(ci, j + 1);
                int i2 = __shfl(ci, j + 2), i3 = __shfl(ci, j + 3);
                int i4 = __shfl(ci, j + 4), i5 = __shfl(ci, j + 5);
                int i6 = __shfl(ci, j + 6), i7 = __shfl(ci, j + 7);
                float t0 = __bfloat162float(Pb[(size_t)i0 * 64 + lane]);
                float t1 = __bfloat162float(Pb[(size_t)i1 * 64 + lane]);
                float t2 = __bfloat162float(Pb[(size_t)i2 * 64 + lane]);
                float t3 = __bfloat162float(Pb[(size_t)i3 * 64 + lane]);
                float t4 = __bfloat162float(Pb[(size_t)i4 * 64 + lane]);
                float t5 = __bfloat162float(Pb[(size_t)i5 * 64 + lane]);
                float t6 = __bfloat162float(Pb[(size_t)i6 * 64 + lane]);
                float t7 = __bfloat162float(Pb[(size_t)i7 * 64 + lane]);
                acc += ((t0 + t1) + (t2 + t3)) + ((t4 + t5) + (t6 + t7));
            }
            for (; j + 4 <= cnt; j += 4) {
                int i0 = __shfl(ci, j + 0), i1 = __shfl(ci, j + 1);
                int i2 = __shfl(ci, j + 2), i3 = __shfl(ci, j + 3);
                float t0 = __bfloat162float(Pb[(size_t)i0 * 64 + lane]);
                float t1 = __bfloat162float(Pb[(size_t)i1 * 64 + lane]);
                float t2 = __bfloat162float(Pb[(size_t)i2 * 64 + lane]);
                float t3 = __bfloat162float(Pb[(size_t)i3 * 64 + lane]);
                acc += (t0 + t1) + (t2 + t3);
            }
            for (; j < cnt; ++j)
                acc += __bfloat162float(Pb[(size_t)__shfl(ci, j) * 64 + lane]);
        }
        float res = acc / fmaxf((float)deg, 1.0f) + q;
        Qh[(size_t)v * 64 + lane] = fmaxf(res, 0.f);
    }
}

// --- Classifier + log_softmax on h rows (stride 64). ---
__global__ __launch_bounds__(256) void cls_kernel(
    const float* __restrict__ h, const float* __restrict__ Wc,
    const float* __restrict__ bc, float* __restrict__ out, int n)
{
    __shared__ float sW[64 * 10];
    __shared__ float sb[16];
    __shared__ float srow[4][4][64];
    int tid = threadIdx.x;
    for (int i = tid; i < 640; i += 256) sW[i] = Wc[i];
    if (tid < 10) sb[tid] = bc[tid];
    __syncthreads();

    int wid = tid >> 6, lane = tid & 63;
    int grp = lane >> 4, l16 = lane & 15;
    int w = blockIdx.x * 4 + wid;
    int nw = gridDim.x * 4;
    int ngroups = (n + 3) >> 2;
    for (int g = w; g < ngroups; g += nw) {
        int v0 = g * 4;
        #pragma unroll
        for (int r = 0; r < 4; ++r) {
            int vv = v0 + r;
            if (vv < n) srow[wid][r][lane] = h[(size_t)vv * 64 + lane];
        }
        int v = v0 + grp;
        float z = -INFINITY;
        if (v < n && l16 < 10) {
            z = sb[l16];
            #pragma unroll
            for (int k = 0; k < 64; ++k)
                z += srow[wid][grp][k] * sW[k * 10 + l16];
        }
        float m = z;
        for (int off = 8; off > 0; off >>= 1)
            m = fmaxf(m, __shfl_xor(m, off, 16));
        float e = (l16 < 10 && v < n) ? expf(z - m) : 0.f;
        float ssum = e;
        for (int off = 8; off > 0; off >>= 1)
            ssum += __shfl_xor(ssum, off, 16);
        if (v < n && l16 < 10)
            out[(size_t)v * 10 + l16] = z - m - logf(ssum);
    }
}

extern "C" void kernel_launch(void* const* d_in, const int* in_sizes, int n_in,
                              void* d_out, int out_size, void* d_ws, size_t ws_size,
                              hipStream_t stream) {
    const float* x   = (const float*)d_in[0];
    const int*   ei  = (const int*)d_in[1];
    const float* Wl1 = (const float*)d_in[2];
    const float* bl1 = (const float*)d_in[3];
    const float* Wr1 = (const float*)d_in[4];
    const float* Wl2 = (const float*)d_in[5];
    const float* bl2 = (const float*)d_in[6];
    const float* Wr2 = (const float*)d_in[7];
    const float* Wl3 = (const float*)d_in[8];
    const float* bl3 = (const float*)d_in[9];
    const float* Wr3 = (const float*)d_in[10];
    const float* Wc  = (const float*)d_in[11];
    const float* bc  = (const float*)d_in[12];
    float* outp = (float*)d_out;

    int n = in_sizes[0] / 64;
    int E = in_sizes[1] / 2;
    const int* srcp = ei;
    const int* dstp = ei + E;
    int nbuck = (n + BUCKET - 1) >> BSHIFT;     // <= MAXB
    int SB = (E + SCAT_EDGES - 1) / SCAT_EDGES;

    char* ws = (char*)d_ws;
    size_t off = 0;
    auto alloc = [&](size_t bytes) -> void* {
        void* p = ws + off;
        off += bytes;
        off = (off + 255) & ~(size_t)255;
        return p;
    };
    int*   ghist  = (int*)alloc((size_t)MAXB * 4);
    int*   bbase  = (int*)alloc((size_t)(MAXB + 1) * 4);
    int*   gcur   = (int*)alloc((size_t)MAXB * 4);
    int*   rowptr = (int*)alloc((size_t)(n + 1) * 4);
    int2*  pairs  = (int2*)alloc((size_t)E * 8);
    int*   colv   = (int*)alloc((size_t)E * 4);
    __hip_bfloat16* Pb = (__hip_bfloat16*)alloc((size_t)n * 64 * 2);
    float* Qh     = (float*)alloc((size_t)n * 64 * 4);
    (void)ws_size; (void)n_in; (void)out_size;

    hipMemsetAsync(ghist, 0, (size_t)MAXB * 4, stream);

    hist_kernel<<<SB, 256, 0, stream>>>(dstp, ghist, E, nbuck);
    scanb_kernel<<<1, 512, 0, stream>>>(ghist, bbase, gcur, nbuck, E);
    scatter_kernel<<<SB, 256, 0, stream>>>(srcp, dstp, gcur, pairs, E, nbuck);
    build_kernel<<<nbuck, 256, 0, stream>>>(pairs, bbase, rowptr, colv, n, E);

    transform_kernel<<<1024, 256, 0, stream>>>(x,  Qh, Pb, Wl1, bl1, Wr1, n);
    gather_kernel<<<2048, 256, 0, stream>>>(Pb, Qh, rowptr, colv, n);
    transform_kernel<<<1024, 256, 0, stream>>>(Qh, Qh, Pb, Wl2, bl2, Wr2, n);
    gather_kernel<<<2048, 256, 0, stream>>>(Pb, Qh, rowptr, colv, n);
    transform_kernel<<<1024, 256, 0, stream>>>(Qh, Qh, Pb, Wl3, bl3, Wr3, n);
    gather_kernel<<<2048, 256, 0, stream>>>(Pb, Qh, rowptr, colv, n);

    cls_kernel<<<1024, 256, 0, stream>>>(Qh, Wc, bc, outp, n);
}

// Round 8
// 410.795 us; speedup vs baseline: 1.7425x; 1.2677x over previous
//
#include <hip/hip_runtime.h>
#include <hip/hip_bf16.h>
#include <math.h>

// ---------------------------------------------------------------------------
// GraphSAGE 3-layer + classifier + log_softmax.  Round 8.
//  - transform rewritten as register-tiled GEMM: 128-node input tile staged in
//    LDS (32KB, coalesced float4), each thread owns one output column with its
//    weight column in 64 VGPRs (launch_bounds(256,4) pins VGPR<=128 so the
//    array stays in registers).  Inner loop: broadcast ds_read_b128 + 4 fma,
//    4-node unroll for ILP.  Replaces the shfl/LDS-serialized version (88us).
//  - CSR bucket sort + bf16 P gather unchanged from round 7.
// ---------------------------------------------------------------------------

#define BSHIFT 8
#define BUCKET 256
#define MAXB 512
#define SCAT_EDGES 8192

__global__ __launch_bounds__(256) void hist_kernel(const int* __restrict__ dst,
                                                   int* __restrict__ ghist,
                                                   int E, int nbuck) {
    __shared__ int lh[MAXB];
    int t = threadIdx.x;
    lh[t] = 0; lh[t + 256] = 0;
    __syncthreads();
    int start = blockIdx.x * SCAT_EDGES;
    int end = min(E, start + SCAT_EDGES);
    for (int e = start + t; e < end; e += 256)
        atomicAdd(&lh[dst[e] >> BSHIFT], 1);
    __syncthreads();
    for (int b = t; b < nbuck; b += 256)
        if (lh[b]) atomicAdd(&ghist[b], lh[b]);
}

__global__ __launch_bounds__(512) void scanb_kernel(const int* __restrict__ ghist,
                                                    int* __restrict__ bbase,
                                                    int* __restrict__ gcur,
                                                    int nbuck, int E) {
    __shared__ int s[MAXB];
    int t = threadIdx.x;
    int v = (t < nbuck) ? ghist[t] : 0;
    s[t] = v;
    __syncthreads();
    for (int off = 1; off < MAXB; off <<= 1) {
        int u = (t >= off) ? s[t - off] : 0;
        __syncthreads();
        s[t] += u;
        __syncthreads();
    }
    int excl = s[t] - v;
    if (t < nbuck) { bbase[t] = excl; gcur[t] = excl; }
    if (t == 0) bbase[nbuck] = E;
}

__global__ __launch_bounds__(256) void scatter_kernel(const int* __restrict__ src,
                                                      const int* __restrict__ dst,
                                                      int* __restrict__ gcur,
                                                      int2* __restrict__ pairs,
                                                      int E, int nbuck) {
    __shared__ int lh[MAXB];
    __shared__ int lbase[MAXB];
    __shared__ int lcur[MAXB];
    int t = threadIdx.x;
    lh[t] = 0; lh[t + 256] = 0;
    lcur[t] = 0; lcur[t + 256] = 0;
    __syncthreads();
    int start = blockIdx.x * SCAT_EDGES;
    int end = min(E, start + SCAT_EDGES);
    for (int e = start + t; e < end; e += 256)
        atomicAdd(&lh[dst[e] >> BSHIFT], 1);
    __syncthreads();
    for (int b = t; b < nbuck; b += 256)
        if (lh[b]) lbase[b] = atomicAdd(&gcur[b], lh[b]);
    __syncthreads();
    for (int e = start + t; e < end; e += 256) {
        int d = dst[e];
        int b = d >> BSHIFT;
        int slot = atomicAdd(&lcur[b], 1);
        pairs[lbase[b] + slot] = make_int2(src[e], d);
    }
}

__global__ __launch_bounds__(256) void build_kernel(const int2* __restrict__ pairs,
                                                    const int* __restrict__ bbase,
                                                    int* __restrict__ rowptr,
                                                    int* __restrict__ col,
                                                    int n, int E) {
    __shared__ int ldeg[BUCKET];
    __shared__ int pre[BUCKET];
    __shared__ int cur[BUCKET];
    int t = threadIdx.x;
    int nbase = blockIdx.x << BSHIFT;
    int e0 = bbase[blockIdx.x], e1 = bbase[blockIdx.x + 1];
    ldeg[t] = 0; cur[t] = 0;
    __syncthreads();
    for (int e = e0 + t; e < e1; e += 256)
        atomicAdd(&ldeg[pairs[e].y - nbase], 1);
    __syncthreads();
    int v = ldeg[t];
    pre[t] = v;
    __syncthreads();
    for (int off = 1; off < 256; off <<= 1) {
        int u = (t >= off) ? pre[t - off] : 0;
        __syncthreads();
        pre[t] += u;
        __syncthreads();
    }
    int excl = pre[t] - v;
    __syncthreads();
    pre[t] = excl;
    __syncthreads();
    int node = nbase + t;
    if (node < n) rowptr[node] = e0 + excl;
    if (blockIdx.x == 0 && t == 0) rowptr[n] = E;
    for (int e = e0 + t; e < e1; e += 256) {
        int2 p = pairs[e];
        int l = p.y - nbase;
        int pos = atomicAdd(&cur[l], 1);
        col[e0 + pre[l] + pos] = p.x;
    }
}

// --- Dense transform as register-tiled GEMM.
// P[v] = in[v]@Wl (bf16 out); Q[v] = in[v]@Wr + bl (f32 out).
// Block stages a 128-node tile in LDS; thread owns one of 128 output columns
// (c<64: P/Wl, c>=64: Q/Wr) with its weight column in 64 VGPRs; node group
// g = tid>>7 covers 64 rows.  All LDS reads are wave-uniform broadcasts.
// In-place safe (in==Qh): block reads only its own rows, writes after sync.
__global__ __launch_bounds__(256, 4) void transform_kernel(
    const float* in, float* Qh, __hip_bfloat16* __restrict__ Pb,
    const float* __restrict__ Wl, const float* __restrict__ bl,
    const float* __restrict__ Wr, int n)
{
    __shared__ float4 tile[2048];       // 128 nodes x 64 feats f32 = 32 KB
    int tid = threadIdx.x;
    int c = tid & 127;
    int g = tid >> 7;
    bool isQ = (c >= 64);
    int f = c & 63;

    const float* W = isQ ? Wr : Wl;
    float w[64];
    #pragma unroll
    for (int k = 0; k < 64; ++k) w[k] = W[k * 64 + f];
    float bias = isQ ? bl[f] : 0.f;

    int base = blockIdx.x * 128;
    int nvalid = n - base; if (nvalid > 128) nvalid = 128;
    const float4* srcp = (const float4*)(in + (size_t)base * 64);
    int nf4 = nvalid * 16;
    for (int i = tid; i < nf4; i += 256) tile[i] = srcp[i];
    __syncthreads();

    for (int q = 0; q < 16; ++q) {
        int r0 = (g << 6) + (q << 2);
        float a0 = bias, a1 = bias, a2 = bias, a3 = bias;
        #pragma unroll
        for (int kq = 0; kq < 16; ++kq) {
            float4 x0 = tile[(r0 + 0) * 16 + kq];
            float4 x1 = tile[(r0 + 1) * 16 + kq];
            float4 x2 = tile[(r0 + 2) * 16 + kq];
            float4 x3 = tile[(r0 + 3) * 16 + kq];
            float w0 = w[4 * kq + 0], w1 = w[4 * kq + 1];
            float w2 = w[4 * kq + 2], w3 = w[4 * kq + 3];
            a0 = fmaf(x0.x, w0, a0); a0 = fmaf(x0.y, w1, a0);
            a0 = fmaf(x0.z, w2, a0); a0 = fmaf(x0.w, w3, a0);
            a1 = fmaf(x1.x, w0, a1); a1 = fmaf(x1.y, w1, a1);
            a1 = fmaf(x1.z, w2, a1); a1 = fmaf(x1.w, w3, a1);
            a2 = fmaf(x2.x, w0, a2); a2 = fmaf(x2.y, w1, a2);
            a2 = fmaf(x2.z, w2, a2); a2 = fmaf(x2.w, w3, a2);
            a3 = fmaf(x3.x, w0, a3); a3 = fmaf(x3.y, w1, a3);
            a3 = fmaf(x3.z, w2, a3); a3 = fmaf(x3.w, w3, a3);
        }
        int v = base + r0;
        if (isQ) {
            if (v + 0 < n) Qh[(size_t)(v + 0) * 64 + f] = a0;
            if (v + 1 < n) Qh[(size_t)(v + 1) * 64 + f] = a1;
            if (v + 2 < n) Qh[(size_t)(v + 2) * 64 + f] = a2;
            if (v + 3 < n) Qh[(size_t)(v + 3) * 64 + f] = a3;
        } else {
            if (v + 0 < n) Pb[(size_t)(v + 0) * 64 + f] = __float2bfloat16(a0);
            if (v + 1 < n) Pb[(size_t)(v + 1) * 64 + f] = __float2bfloat16(a1);
            if (v + 2 < n) Pb[(size_t)(v + 2) * 64 + f] = __float2bfloat16(a2);
            if (v + 3 < n) Pb[(size_t)(v + 3) * 64 + f] = __float2bfloat16(a3);
        }
    }
}

// --- Pure-memory gather: h[v] = relu( mean_{s in N(v)} P[s] + Q[v] ) -> Qh[v].
__global__ __launch_bounds__(256) void gather_kernel(
    const __hip_bfloat16* __restrict__ Pb, float* __restrict__ Qh,
    const int* __restrict__ rowptr, const int* __restrict__ col, int n)
{
    int tid = threadIdx.x;
    int wid = tid >> 6, lane = tid & 63;
    int w = blockIdx.x * 4 + wid;
    int nw = gridDim.x * 4;
    for (int v = w; v < n; v += nw) {
        int s0 = rowptr[v], s1 = rowptr[v + 1];
        int deg = s1 - s0;
        float q = Qh[(size_t)v * 64 + lane];
        float acc = 0.f;
        for (int base = 0; base < deg; base += 64) {
            int rem = deg - base;
            int cnt = rem < 64 ? rem : 64;
            int ci = (lane < cnt) ? col[s0 + base + lane] : 0;
            int j = 0;
            for (; j + 8 <= cnt; j += 8) {
                int i0 = __shfl(ci, j + 0), i1 = __shfl(ci, j + 1);
                int i2 = __shfl(ci, j + 2), i3 = __shfl(ci, j + 3);
                int i4 = __shfl(ci, j + 4), i5 = __shfl(ci, j + 5);
                int i6 = __shfl(ci, j + 6), i7 = __shfl(ci, j + 7);
                float t0 = __bfloat162float(Pb[(size_t)i0 * 64 + lane]);
                float t1 = __bfloat162float(Pb[(size_t)i1 * 64 + lane]);
                float t2 = __bfloat162float(Pb[(size_t)i2 * 64 + lane]);
                float t3 = __bfloat162float(Pb[(size_t)i3 * 64 + lane]);
                float t4 = __bfloat162float(Pb[(size_t)i4 * 64 + lane]);
                float t5 = __bfloat162float(Pb[(size_t)i5 * 64 + lane]);
                float t6 = __bfloat162float(Pb[(size_t)i6 * 64 + lane]);
                float t7 = __bfloat162float(Pb[(size_t)i7 * 64 + lane]);
                acc += ((t0 + t1) + (t2 + t3)) + ((t4 + t5) + (t6 + t7));
            }
            for (; j + 4 <= cnt; j += 4) {
                int i0 = __shfl(ci, j + 0), i1 = __shfl(ci, j + 1);
                int i2 = __shfl(ci, j + 2), i3 = __shfl(ci, j + 3);
                float t0 = __bfloat162float(Pb[(size_t)i0 * 64 + lane]);
                float t1 = __bfloat162float(Pb[(size_t)i1 * 64 + lane]);
                float t2 = __bfloat162float(Pb[(size_t)i2 * 64 + lane]);
                float t3 = __bfloat162float(Pb[(size_t)i3 * 64 + lane]);
                acc += (t0 + t1) + (t2 + t3);
            }
            for (; j < cnt; ++j)
                acc += __bfloat162float(Pb[(size_t)__shfl(ci, j) * 64 + lane]);
        }
        float res = acc / fmaxf((float)deg, 1.0f) + q;
        Qh[(size_t)v * 64 + lane] = fmaxf(res, 0.f);
    }
}

// --- Classifier + log_softmax on h rows (stride 64). ---
__global__ __launch_bounds__(256) void cls_kernel(
    const float* __restrict__ h, const float* __restrict__ Wc,
    const float* __restrict__ bc, float* __restrict__ out, int n)
{
    __shared__ float sW[64 * 10];
    __shared__ float sb[16];
    __shared__ float srow[4][4][64];
    int tid = threadIdx.x;
    for (int i = tid; i < 640; i += 256) sW[i] = Wc[i];
    if (tid < 10) sb[tid] = bc[tid];
    __syncthreads();

    int wid = tid >> 6, lane = tid & 63;
    int grp = lane >> 4, l16 = lane & 15;
    int w = blockIdx.x * 4 + wid;
    int nw = gridDim.x * 4;
    int ngroups = (n + 3) >> 2;
    for (int g = w; g < ngroups; g += nw) {
        int v0 = g * 4;
        #pragma unroll
        for (int r = 0; r < 4; ++r) {
            int vv = v0 + r;
            if (vv < n) srow[wid][r][lane] = h[(size_t)vv * 64 + lane];
        }
        int v = v0 + grp;
        float z = -INFINITY;
        if (v < n && l16 < 10) {
            z = sb[l16];
            #pragma unroll
            for (int k = 0; k < 64; ++k)
                z += srow[wid][grp][k] * sW[k * 10 + l16];
        }
        float m = z;
        for (int off = 8; off > 0; off >>= 1)
            m = fmaxf(m, __shfl_xor(m, off, 16));
        float e = (l16 < 10 && v < n) ? expf(z - m) : 0.f;
        float ssum = e;
        for (int off = 8; off > 0; off >>= 1)
            ssum += __shfl_xor(ssum, off, 16);
        if (v < n && l16 < 10)
            out[(size_t)v * 10 + l16] = z - m - logf(ssum);
    }
}

extern "C" void kernel_launch(void* const* d_in, const int* in_sizes, int n_in,
                              void* d_out, int out_size, void* d_ws, size_t ws_size,
                              hipStream_t stream) {
    const float* x   = (const float*)d_in[0];
    const int*   ei  = (const int*)d_in[1];
    const float* Wl1 = (const float*)d_in[2];
    const float* bl1 = (const float*)d_in[3];
    const float* Wr1 = (const float*)d_in[4];
    const float* Wl2 = (const float*)d_in[5];
    const float* bl2 = (const float*)d_in[6];
    const float* Wr2 = (const float*)d_in[7];
    const float* Wl3 = (const float*)d_in[8];
    const float* bl3 = (const float*)d_in[9];
    const float* Wr3 = (const float*)d_in[10];
    const float* Wc  = (const float*)d_in[11];
    const float* bc  = (const float*)d_in[12];
    float* outp = (float*)d_out;

    int n = in_sizes[0] / 64;
    int E = in_sizes[1] / 2;
    const int* srcp = ei;
    const int* dstp = ei + E;
    int nbuck = (n + BUCKET - 1) >> BSHIFT;
    int SB = (E + SCAT_EDGES - 1) / SCAT_EDGES;
    int ntile = (n + 127) / 128;

    char* ws = (char*)d_ws;
    size_t off = 0;
    auto alloc = [&](size_t bytes) -> void* {
        void* p = ws + off;
        off += bytes;
        off = (off + 255) & ~(size_t)255;
        return p;
    };
    int*   ghist  = (int*)alloc((size_t)MAXB * 4);
    int*   bbase  = (int*)alloc((size_t)(MAXB + 1) * 4);
    int*   gcur   = (int*)alloc((size_t)MAXB * 4);
    int*   rowptr = (int*)alloc((size_t)(n + 1) * 4);
    int2*  pairs  = (int2*)alloc((size_t)E * 8);
    int*   colv   = (int*)alloc((size_t)E * 4);
    __hip_bfloat16* Pb = (__hip_bfloat16*)alloc((size_t)n * 64 * 2);
    float* Qh     = (float*)alloc((size_t)n * 64 * 4);
    (void)ws_size; (void)n_in; (void)out_size;

    hipMemsetAsync(ghist, 0, (size_t)MAXB * 4, stream);

    hist_kernel<<<SB, 256, 0, stream>>>(dstp, ghist, E, nbuck);
    scanb_kernel<<<1, 512, 0, stream>>>(ghist, bbase, gcur, nbuck, E);
    scatter_kernel<<<SB, 256, 0, stream>>>(srcp, dstp, gcur, pairs, E, nbuck);
    build_kernel<<<nbuck, 256, 0, stream>>>(pairs, bbase, rowptr, colv, n, E);

    transform_kernel<<<ntile, 256, 0, stream>>>(x,  Qh, Pb, Wl1, bl1, Wr1, n);
    gather_kernel<<<2048, 256, 0, stream>>>(Pb, Qh, rowptr, colv, n);
    transform_kernel<<<ntile, 256, 0, stream>>>(Qh, Qh, Pb, Wl2, bl2, Wr2, n);
    gather_kernel<<<2048, 256, 0, stream>>>(Pb, Qh, rowptr, colv, n);
    transform_kernel<<<ntile, 256, 0, stream>>>(Qh, Qh, Pb, Wl3, bl3, Wr3, n);
    gather_kernel<<<2048, 256, 0, stream>>>(Pb, Qh, rowptr, colv, n);

    cls_kernel<<<1024, 256, 0, stream>>>(Qh, Wc, bc, outp, n);
}